// Round 8
// baseline (112.377 us; speedup 1.0000x reference)
//
#include <hip/hip_runtime.h>
#include <hip/hip_bf16.h>

// Problem constants
#define B    2
#define CIN  256
#define H    56
#define W    56
#define OUTC 256
#define KS   7
#define PAD  3
#define G    8
#define CG   32
#define HP   62           // H + 2*PAD
#define WP   62
#define P1   (H * W)      // 3136
#define P2   (HP * WP)    // 3844

typedef __attribute__((ext_vector_type(2))) _Float16 h2;
typedef __attribute__((ext_vector_type(8))) _Float16 f16x8;
typedef __attribute__((ext_vector_type(4))) float f32x4;

__device__ inline unsigned short f2h(float f) {    // RNE float->fp16 bits
    const _Float16 h = (_Float16)f;
    return *(const unsigned short*)&h;
}

__device__ inline float fdot2(h2 a, h2 b, float c) {
#if defined(__has_builtin)
#if __has_builtin(__builtin_amdgcn_fdot2)
    return __builtin_amdgcn_fdot2(a, b, c, false);
#else
    return c + (float)a[0] * (float)b[0] + (float)a[1] * (float)b[1];
#endif
#else
    return c + (float)a[0] * (float)b[0] + (float)a[1] * (float)b[1];
#endif
}

__device__ inline float dot8(const f16x8 q, const f16x8 k, float s) {
    s = fdot2((h2){q[0], q[1]}, (h2){k[0], k[1]}, s);
    s = fdot2((h2){q[2], q[3]}, (h2){k[2], k[3]}, s);
    s = fdot2((h2){q[4], q[5]}, (h2){k[4], k[5]}, s);
    s = fdot2((h2){q[6], q[7]}, (h2){k[6], k[7]}, s);
    return s;
}

// ---------------------------------------------------------------------------
// Fused fp32->fp16 + MFMA GEMM: grid (31, 6, B).  (unchanged from R6/R7)
//   y<2  : q GEMM  (w_q x fm_t1), x<25 only (N=P1)
//   y>=2 : kv GEMM (w_k rows 0..255, w_v rows 256..511 x padded fm_t0, N=P2)
// 128x128 tile, 4 waves, BK=32; staging converts fp32 inputs inline.
// Double-buffered LDS -> one barrier per K-step.
// Epilogue writes fp16 INTERLEAVED planes: base[((b*8+g)*4+sub)*Pstr+n]*8+l8.
// ---------------------------------------------------------------------------
#define ASTR 40
__global__ __launch_bounds__(256, 2) void gemm_kernel(const float* __restrict__ fm,
                                                      const float* __restrict__ wq,
                                                      const float* __restrict__ wk,
                                                      const float* __restrict__ wv,
                                                      unsigned short* __restrict__ qi,
                                                      unsigned short* __restrict__ ki,
                                                      unsigned short* __restrict__ vi) {
    const int b = blockIdx.z;
    const bool isQ = blockIdx.y < 2;
    if (isQ && blockIdx.x >= 25) return;
    const int o0 = (isQ ? blockIdx.y : (blockIdx.y - 2)) * 128;   // 0..383
    const int n0 = blockIdx.x * 128;
    const int Nreal = isQ ? P1 : P2;
    const int Pstr  = isQ ? P1 : P2;

    const float* Wsrc;
    int orow0;
    if (isQ)            { Wsrc = wq; orow0 = o0; }
    else if (o0 < 256)  { Wsrc = wk; orow0 = o0; }
    else                { Wsrc = wv; orow0 = o0 - 256; }

    __shared__ unsigned short Alds[2][128 * ASTR];
    __shared__ unsigned short Blds[2][128 * ASTR];
    const int tid = threadIdx.x;
    const int lane = tid & 63;
    const int wave = tid >> 6;
    const int wr = (wave >> 1) * 64;
    const int wc = (wave & 1) * 64;
    const int lrow = lane & 15;
    const int quad = lane >> 4;

    const int arow = tid & 127;
    const int akc  = (tid >> 7) * 16;

    const int n = n0 + arow;
    int srcoff = -1;
    if (isQ) {
        if (n < P1) srcoff = n;
    } else {
        if (n < P2) {
            const int y = n / WP, x = n - y * WP;
            const int iy = y - PAD, ix = x - PAD;
            if (iy >= 0 && iy < H && ix >= 0 && ix < W) srcoff = iy * W + ix;
        }
    }
    const float* fmB = fm + ((size_t)b * (2 * CIN) + (isQ ? CIN : 0)) * P1;
    const float* wrow = Wsrc + (size_t)orow0 * CIN + (size_t)arow * CIN + akc;

    f32x4 acc[4][4] = {};

    float av[16], bv[16];
    {
        const float4 a0 = ((const float4*)wrow)[0];
        const float4 a1 = ((const float4*)wrow)[1];
        const float4 a2 = ((const float4*)wrow)[2];
        const float4 a3 = ((const float4*)wrow)[3];
        av[0]=a0.x; av[1]=a0.y; av[2]=a0.z; av[3]=a0.w;
        av[4]=a1.x; av[5]=a1.y; av[6]=a1.z; av[7]=a1.w;
        av[8]=a2.x; av[9]=a2.y; av[10]=a2.z; av[11]=a2.w;
        av[12]=a3.x; av[13]=a3.y; av[14]=a3.z; av[15]=a3.w;
        #pragma unroll
        for (int j = 0; j < 16; ++j)
            bv[j] = (srcoff >= 0) ? fmB[(size_t)(akc + j) * P1 + srcoff] : 0.f;
    }

    for (int kb = 0; kb < CIN / 32; ++kb) {
        const int cur = kb & 1;
        unsigned short* alp = Alds[cur] + arow * ASTR + akc;
        unsigned short* blp = Blds[cur] + arow * ASTR + akc;
        {
            f16x8 p0, p1, p2, p3;
            #pragma unroll
            for (int j = 0; j < 8; ++j) {
                p0[j] = (_Float16)av[j];
                p1[j] = (_Float16)av[8 + j];
                p2[j] = (_Float16)bv[j];
                p3[j] = (_Float16)bv[8 + j];
            }
            *(f16x8*)(alp)     = p0;
            *(f16x8*)(alp + 8) = p1;
            *(f16x8*)(blp)     = p2;
            *(f16x8*)(blp + 8) = p3;
        }
        __syncthreads();                    // buf[cur] staged; one barrier/step
        if (kb < CIN / 32 - 1) {
            const int c0 = (kb + 1) * 32 + akc;
            const float* wnext = wrow + (kb + 1) * 32;
            const float4 a0 = ((const float4*)wnext)[0];
            const float4 a1 = ((const float4*)wnext)[1];
            const float4 a2 = ((const float4*)wnext)[2];
            const float4 a3 = ((const float4*)wnext)[3];
            av[0]=a0.x; av[1]=a0.y; av[2]=a0.z; av[3]=a0.w;
            av[4]=a1.x; av[5]=a1.y; av[6]=a1.z; av[7]=a1.w;
            av[8]=a2.x; av[9]=a2.y; av[10]=a2.z; av[11]=a2.w;
            av[12]=a3.x; av[13]=a3.y; av[14]=a3.z; av[15]=a3.w;
            #pragma unroll
            for (int j = 0; j < 16; ++j)
                bv[j] = (srcoff >= 0) ? fmB[(size_t)(c0 + j) * P1 + srcoff] : 0.f;
        }
        f16x8 af[4], bfr[4];
        #pragma unroll
        for (int mi = 0; mi < 4; ++mi)
            af[mi] = *(const f16x8*)&Alds[cur][(wr + mi * 16 + lrow) * ASTR + quad * 8];
        #pragma unroll
        for (int ni = 0; ni < 4; ++ni)
            bfr[ni] = *(const f16x8*)&Blds[cur][(wc + ni * 16 + lrow) * ASTR + quad * 8];
        #pragma unroll
        for (int mi = 0; mi < 4; ++mi)
            #pragma unroll
            for (int ni = 0; ni < 4; ++ni)
                acc[mi][ni] = __builtin_amdgcn_mfma_f32_16x16x32_f16(af[mi], bfr[ni], acc[mi][ni], 0, 0, 0);
    }

    #pragma unroll
    for (int mi = 0; mi < 4; ++mi) {
        const int gmBase = o0 + wr + mi * 16 + quad * 4;
        int ch0;
        unsigned short* base;
        if (isQ)               { ch0 = gmBase;       base = qi; }
        else if (gmBase < 256) { ch0 = gmBase;       base = ki; }
        else                   { ch0 = gmBase - 256; base = vi; }
        const int g   = ch0 >> 5;
        const int sub = (ch0 >> 3) & 3;
        const int l8  = ch0 & 7;
        unsigned short* pbase = base + ((((size_t)b * 8 + g) * 4 + sub) * Pstr) * 8 + l8;
        #pragma unroll
        for (int ni = 0; ni < 4; ++ni) {
            const int gn = n0 + wc + ni * 16 + lrow;
            if (gn < Nreal) {
                ushort4 pk;
                pk.x = f2h(acc[mi][ni][0]);
                pk.y = f2h(acc[mi][ni][1]);
                pk.z = f2h(acc[mi][ni][2]);
                pk.w = f2h(acc[mi][ni][3]);
                *(ushort4*)(pbase + (size_t)gn * 8) = pk;
            }
        }
    }
}

// ---------------------------------------------------------------------------
// Grouped 7x7 attention: SINGLE-STAGE, SINGLE-BARRIER.
// 2-row strip per (b,g): grid (28, 8, 2) = 448 blocks x 128 thr, 56
// compute-active (cx = tid; pixels r0, r0+1). The full 2-row window working
// set (K+V, all 4 subs, 8 padded rows x 62) = 63,488 B fits LDS -> stage
// EVERYTHING once (32 independent global loads in flight, one drain), one
// __syncthreads, then the entire QK -> softmax -> PV compute is barrier-
// free. R7's 4-barrier channel-split pipeline exposed 4 serialized
// global->LDS latency rounds; this exposes 1. LDS 63.5 KB -> 2 blocks/CU
// (127 KB < 160 KB) for cross-block overlap of the single staging round.
// Window rows r0..r0+7 are CONTIGUOUS in each padded plane (496 f16x8).
// Read sharing: per tap-col j, 8 row-reads (ii=0..7) serve pixel0 taps
// ii<7 and pixel1 taps ii>=1; lane stride 16 B (conflict-free).
// ---------------------------------------------------------------------------
#define NPOS 496     // 8 * 62 window positions
__global__ __launch_bounds__(128) void attn_kernel(const unsigned short* __restrict__ qi,
                                                   const unsigned short* __restrict__ ki,
                                                   const unsigned short* __restrict__ vi,
                                                   const float* __restrict__ rel_h,
                                                   const float* __restrict__ rel_w,
                                                   float* __restrict__ out) {
    __shared__ f16x8 sbuf[8 * NPOS];    // [kv][sub][pos] = 63,488 B

    const int b  = blockIdx.z;
    const int g  = blockIdx.y;
    const int r0 = blockIdx.x * 2;      // first pixel row of 2-row strip
    const int oc0 = g * CG;
    const int tid = threadIdx.x;
    const bool active = tid < 56;
    const int cx = tid;                 // 0..55 (when active)
    const int pix0 = r0 * W + cx;
    const int pix1 = pix0 + W;

    const size_t bg4 = ((size_t)b * 8 + g) * 4;
    const int woff = r0 * WP;           // window start (contiguous 496 elems)

    f16x8* bufK = sbuf;
    f16x8* bufV = sbuf + 4 * NPOS;

    // q for both pixels (issued before staging)
    f16x8 qh0[4], qh1[4];
    if (active) {
        #pragma unroll
        for (int sub = 0; sub < 4; ++sub) {
            qh0[sub] = *(const f16x8*)(qi + ((bg4 + sub) * P1 + pix0) * 8);
            qh1[sub] = *(const f16x8*)(qi + ((bg4 + sub) * P1 + pix1) * 8);
        }
    }

    // ---- stage K and V (all 4 subs each) in ONE round ----
    f16x8 stK[16], stV[16];
    #pragma unroll
    for (int sub = 0; sub < 4; ++sub) {
        const unsigned short* gk = ki + ((bg4 + sub) * P2 + woff) * 8;
        #pragma unroll
        for (int it = 0; it < 4; ++it) {
            const int e = tid + it * 128;
            if (e < NPOS) stK[sub * 4 + it] = *(const f16x8*)(gk + (size_t)e * 8);
        }
    }
    #pragma unroll
    for (int sub = 0; sub < 4; ++sub) {
        const unsigned short* gv = vi + ((bg4 + sub) * P2 + woff) * 8;
        #pragma unroll
        for (int it = 0; it < 4; ++it) {
            const int e = tid + it * 128;
            if (e < NPOS) stV[sub * 4 + it] = *(const f16x8*)(gv + (size_t)e * 8);
        }
    }
    #pragma unroll
    for (int sub = 0; sub < 4; ++sub)
        #pragma unroll
        for (int it = 0; it < 4; ++it) {
            const int e = tid + it * 128;
            if (e < NPOS) bufK[sub * NPOS + e] = stK[sub * 4 + it];
        }
    #pragma unroll
    for (int sub = 0; sub < 4; ++sub)
        #pragma unroll
        for (int it = 0; it < 4; ++it) {
            const int e = tid + it * 128;
            if (e < NPOS) bufV[sub * NPOS + e] = stV[sub * 4 + it];
        }
    __syncthreads();   // the ONLY barrier

    if (!active) return;   // staging-only lanes done (no further barriers)

    // ---- bias init per pixel (shared rel loads, SGPR-uniform) ----
    float logits0[KS * KS], logits1[KS * KS];
    {
        const float* rel = (g < 4) ? (rel_h + oc0 * KS) : (rel_w + (oc0 - 128) * KS);
        float qf0[32], qf1[32];
        #pragma unroll
        for (int sub = 0; sub < 4; ++sub)
            #pragma unroll
            for (int j = 0; j < 8; ++j) {
                qf0[sub * 8 + j] = (float)qh0[sub][j];
                qf1[sub * 8 + j] = (float)qh1[sub][j];
            }
        float bd0[KS], bd1[KS];
        #pragma unroll
        for (int t = 0; t < KS; ++t) {
            float s0 = 0.f, s1 = 0.f;
            #pragma unroll
            for (int c = 0; c < 32; ++c) {
                const float r = rel[c * KS + t];
                s0 += qf0[c] * r;
                s1 += qf1[c] * r;
            }
            bd0[t] = s0; bd1[t] = s1;
        }
        #pragma unroll
        for (int i = 0; i < KS; ++i)
            #pragma unroll
            for (int j = 0; j < KS; ++j) {
                logits0[i * KS + j] = (g < 4) ? bd0[i] : bd0[j];
                logits1[i * KS + j] = (g < 4) ? bd1[i] : bd1[j];
            }
    }

    // ---- QK^T: all 4 subs, row-shared reads ----
    #pragma unroll
    for (int s = 0; s < 4; ++s) {
        const f16x8 q0 = qh0[s];
        const f16x8 q1 = qh1[s];
        #pragma unroll
        for (int j = 0; j < KS; ++j) {
            #pragma unroll
            for (int ii = 0; ii < 8; ++ii) {
                const f16x8 kv = bufK[s * NPOS + ii * WP + cx + j];
                if (ii < 7)  logits0[ii * KS + j]       = dot8(q0, kv, logits0[ii * KS + j]);
                if (ii >= 1) logits1[(ii - 1) * KS + j] = dot8(q1, kv, logits1[(ii - 1) * KS + j]);
            }
        }
    }

    // ---- softmax per pixel ----
    {
        float m = logits0[0];
        #pragma unroll
        for (int t = 1; t < KS * KS; ++t) m = fmaxf(m, logits0[t]);
        float sum = 0.f;
        #pragma unroll
        for (int t = 0; t < KS * KS; ++t) {
            const float e = __expf(logits0[t] - m);
            logits0[t] = e;
            sum += e;
        }
        const float inv = 1.f / sum;
        #pragma unroll
        for (int t = 0; t < KS * KS; ++t) logits0[t] *= inv;
    }
    {
        float m = logits1[0];
        #pragma unroll
        for (int t = 1; t < KS * KS; ++t) m = fmaxf(m, logits1[t]);
        float sum = 0.f;
        #pragma unroll
        for (int t = 0; t < KS * KS; ++t) {
            const float e = __expf(logits1[t] - m);
            logits1[t] = e;
            sum += e;
        }
        const float inv = 1.f / sum;
        #pragma unroll
        for (int t = 0; t < KS * KS; ++t) logits1[t] *= inv;
    }

    // ---- PV: all 4 subs -> channels oc0 + s*8 ----
    #pragma unroll
    for (int s = 0; s < 4; ++s) {
        float a0[8] = {}, a1[8] = {};
        #pragma unroll
        for (int j = 0; j < KS; ++j) {
            #pragma unroll
            for (int ii = 0; ii < 8; ++ii) {
                const f16x8 v = bufV[s * NPOS + ii * WP + cx + j];
                if (ii < 7) {
                    const float wt = logits0[ii * KS + j];
                    #pragma unroll
                    for (int c = 0; c < 8; ++c) a0[c] += wt * (float)v[c];
                }
                if (ii >= 1) {
                    const float wt = logits1[(ii - 1) * KS + j];
                    #pragma unroll
                    for (int c = 0; c < 8; ++c) a1[c] += wt * (float)v[c];
                }
            }
        }
        float* op0 = out + ((size_t)b * OUTC + oc0 + s * 8) * P1 + pix0;
        float* op1 = out + ((size_t)b * OUTC + oc0 + s * 8) * P1 + pix1;
        #pragma unroll
        for (int c = 0; c < 8; ++c) {
            op0[(size_t)c * P1] = a0[c];
            op1[(size_t)c * P1] = a1[c];
        }
    }
}

extern "C" void kernel_launch(void* const* d_in, const int* in_sizes, int n_in,
                              void* d_out, int out_size, void* d_ws, size_t ws_size,
                              hipStream_t stream) {
    const float* fm = (const float*)d_in[0];
    const float* wq = (const float*)d_in[1];
    const float* wk = (const float*)d_in[2];
    const float* wv = (const float*)d_in[3];
    const float* rh = (const float*)d_in[4];
    const float* rw = (const float*)d_in[5];
    float* out = (float*)d_out;

    unsigned short* ws = (unsigned short*)d_ws;
    unsigned short* qi = ws;                             // 2*8*4*3136*8 fp16
    unsigned short* ki = qi + (size_t)B * OUTC * P1;     // 2*8*4*3844*8 fp16
    unsigned short* vi = ki + (size_t)B * OUTC * P2;

    gemm_kernel<<<dim3(31, 6, B), 256, 0, stream>>>(fm, wq, wk, wv, qi, ki, vi);
    attn_kernel<<<dim3(H / 2, G, B), 128, 0, stream>>>(qi, ki, vi, rh, rw, out);
}